// Round 4
// baseline (510.174 us; speedup 1.0000x reference)
//
#include <hip/hip_runtime.h>

typedef __bf16 bf16_t;
typedef __bf16 bf16x4 __attribute__((ext_vector_type(4)));
typedef __bf16 bf16x8 __attribute__((ext_vector_type(8)));
typedef float f32x4 __attribute__((ext_vector_type(4)));

#define N_PIX 4096
#define CFEAT 256
#define CKEY 32
#define NBATCH 4

static __device__ __forceinline__ f32x4 mfma16(bf16x8 a, bf16x8 b, f32x4 c) {
    return __builtin_amdgcn_mfma_f32_16x16x32_bf16(a, b, c, 0, 0, 0);
}

// ---------------------------------------------------------------------------
// transpose_kernel: XT[b][n][c] = bf16(X[b][c][n]) for features and conditions.
// Coalesced f32x4 loads -> LDS tile -> coalesced bf16x8 stores.
// grid (N/64, C/64, 2*B), block 256.
// ---------------------------------------------------------------------------
__global__ __launch_bounds__(256) void transpose_kernel(
    const float* __restrict__ Xf, const float* __restrict__ Xc,
    bf16_t* __restrict__ XTf, bf16_t* __restrict__ XTc)
{
    __shared__ __attribute__((aligned(16))) bf16_t Ts[64][68];   // [c][n], +4 pad
    const int t = threadIdx.x;
    const int b = blockIdx.z & 3;
    const bool isC = blockIdx.z >= 4;
    const float* X  = (isC ? Xc : Xf) + (size_t)b * CFEAT * N_PIX;
    bf16_t*      XT = (isC ? XTc : XTf) + (size_t)b * N_PIX * CFEAT;
    const int c0 = blockIdx.y * 64, n0 = blockIdx.x * 64;

#pragma unroll
    for (int p = 0; p < 4; ++p) {
        const int c = (t >> 4) + p * 16;
        const int n = (t & 15) * 4;
        const f32x4 x = *(const f32x4*)&X[(size_t)(c0 + c) * N_PIX + n0 + n];
        bf16x4 v;
#pragma unroll
        for (int e = 0; e < 4; ++e) v[e] = (bf16_t)x[e];
        *(bf16x4*)&Ts[c][n] = v;
    }
    __syncthreads();
#pragma unroll
    for (int p = 0; p < 2; ++p) {
        const int n  = (t >> 3) + p * 32;
        const int cs = (t & 7) * 8;
        bf16x8 v;
#pragma unroll
        for (int e = 0; e < 8; ++e) v[e] = Ts[cs + e][n];
        *(bf16x8*)&XT[(size_t)(n0 + n) * CFEAT + c0 + cs] = v;
    }
}

// ---------------------------------------------------------------------------
// projqk: Qt[b][n][32] = Wq.cond + bq ; Kt[b][n][32] = Wk.feat + bk.
// A = XT rows (m = n-pixels, contiguous 16B), B = W^T (hoisted for all 8
// k-steps). D[row=n_local][col=ck] stores directly in transposed layout.
// grid (N/32, B), block 256: waves 0,1 = Q (n-tiles 0,1), waves 2,3 = K.
// ---------------------------------------------------------------------------
__global__ __launch_bounds__(256) void projqk_kernel(
    const float* __restrict__ Wq, const float* __restrict__ bq,
    const float* __restrict__ Wk, const float* __restrict__ bk,
    const bf16_t* __restrict__ XTc, const bf16_t* __restrict__ XTf,
    bf16_t* __restrict__ Qt, bf16_t* __restrict__ Kt)
{
    const int lane = threadIdx.x & 63, wave = threadIdx.x >> 6;
    const int g = lane >> 4, ln = lane & 15;
    const int b = blockIdx.y;
    const bool isK = wave >= 2;
    const int n_base = blockIdx.x * 32 + (wave & 1) * 16;
    const float* W    = isK ? Wk : Wq;
    const float* bias = isK ? bk : bq;
    const bf16_t* XT = (isK ? XTf : XTc) + (size_t)b * N_PIX * CFEAT;
    bf16_t* Yt = (isK ? Kt : Qt) + (size_t)b * N_PIX * CKEY;

    // hoisted W^T B-frags: wf[s][h] = B[k=s*32+g*8+j][ck=h*16+ln]
    bf16x8 wf[8][2];
#pragma unroll
    for (int s = 0; s < 8; ++s)
#pragma unroll
        for (int h = 0; h < 2; ++h) {
            const float* wp = W + (size_t)(h * 16 + ln) * CFEAT + s * 32 + g * 8;
#pragma unroll
            for (int j = 0; j < 8; ++j) wf[s][h][j] = (bf16_t)wp[j];
        }
    f32x4 zero = {0.f, 0.f, 0.f, 0.f};
    f32x4 acc[2] = {zero, zero};
#pragma unroll
    for (int s = 0; s < 8; ++s) {
        const bf16x8 af = *(const bf16x8*)&XT[(size_t)(n_base + ln) * CFEAT + s * 32 + g * 8];
        acc[0] = mfma16(af, wf[s][0], acc[0]);
        acc[1] = mfma16(af, wf[s][1], acc[1]);
    }
#pragma unroll
    for (int h = 0; h < 2; ++h)
#pragma unroll
        for (int r = 0; r < 4; ++r)
            Yt[(size_t)(n_base + g * 4 + r) * CKEY + h * 16 + ln] =
                (bf16_t)(acc[h][r] + bias[h * 16 + ln]);
}

// ---------------------------------------------------------------------------
// projv: V[b][c][n] = Wv.feat + bv.  A = Wv rows (hoisted 8 steps),
// B = XT rows (contiguous 16B). grid (N/64, C/64, B) = 1024 blocks, block 256;
// wave = one 16-c tile, 4 n-frags.
// ---------------------------------------------------------------------------
__global__ __launch_bounds__(256, 4) void projv_kernel(
    const float* __restrict__ W, const float* __restrict__ bias,
    const bf16_t* __restrict__ XTf, bf16_t* __restrict__ V)
{
    const int lane = threadIdx.x & 63, wave = threadIdx.x >> 6;
    const int g = lane >> 4, ln = lane & 15;
    const int b = blockIdx.z;
    const int c_w = blockIdx.y * 64 + wave * 16;
    const int n_base = blockIdx.x * 64;
    const bf16_t* XT = XTf + (size_t)b * N_PIX * CFEAT;
    bf16_t* Vb = V + (size_t)b * CFEAT * N_PIX;

    bf16x8 af[8];
#pragma unroll
    for (int s = 0; s < 8; ++s) {
        const float* wp = W + (size_t)(c_w + ln) * CFEAT + s * 32 + g * 8;
#pragma unroll
        for (int j = 0; j < 8; ++j) af[s][j] = (bf16_t)wp[j];
    }
    f32x4 zero = {0.f, 0.f, 0.f, 0.f};
    f32x4 acc[4] = {zero, zero, zero, zero};
#pragma unroll 2
    for (int s = 0; s < 8; ++s) {
        bf16x8 bf[4];
#pragma unroll
        for (int nt = 0; nt < 4; ++nt)
            bf[nt] = *(const bf16x8*)&XT[(size_t)(n_base + nt * 16 + ln) * CFEAT + s * 32 + g * 8];
#pragma unroll
        for (int nt = 0; nt < 4; ++nt) acc[nt] = mfma16(af[s], bf[nt], acc[nt]);
    }
#pragma unroll
    for (int nt = 0; nt < 4; ++nt)
#pragma unroll
        for (int r = 0; r < 4; ++r)
            Vb[(size_t)(c_w + g * 4 + r) * N_PIX + n_base + nt * 16 + ln] =
                (bf16_t)(acc[nt][r] + bias[c_w + g * 4 + r]);
}

// ---------------------------------------------------------------------------
// pv: out = gamma * softmax(QK^T) V / l + features, max-free softmax.
// S^T = K.Q^T (per-lane col = i). EXPLICIT 1-iter software pipeline:
//   - V(n+1) loaded during iter n (vcur/vnxt rotation)
//   - K prefetched 2 tiles ahead
//   - P double-buffered in per-wave LDS: write P(n+1) while PV consumes P(n)
// No barriers. grid (4, N/64, B) = 1024 blocks, block 256, 3 waves/SIMD cap.
// ---------------------------------------------------------------------------
#define PSTRIDE 72   // elems; 144B rows: 16B-aligned b128 reads
__global__ __launch_bounds__(256, 3) void pv_kernel(
    const bf16_t* __restrict__ Qt, const bf16_t* __restrict__ Kt,
    const bf16_t* __restrict__ V,
    const float* __restrict__ features, const float* __restrict__ gamma,
    float* __restrict__ out)
{
    __shared__ __attribute__((aligned(16))) bf16_t Plds[4][2][16 * PSTRIDE];
    const int lane = threadIdx.x & 63, wave = threadIdx.x >> 6;
    const int g = lane >> 4, ln = lane & 15;
    const int b = blockIdx.z;
    const int i_base = blockIdx.y * 64 + wave * 16;
    const int c_base = blockIdx.x * 64;

    const bf16_t* Qb = Qt + (size_t)b * N_PIX * CKEY;
    const bf16_t* Kb = Kt + (size_t)b * N_PIX * CKEY;
    const bf16_t* Vb = V + (size_t)b * CFEAT * N_PIX;

    // B-frag for S^T: B[k=ck][n=i=ln] = Qt[i][ck]
    const bf16x8 qf = *(const bf16x8*)&Qb[(size_t)(i_base + ln) * CKEY + g * 8];

    f32x4 zero = {0.f, 0.f, 0.f, 0.f};
    f32x4 acc[4] = {zero, zero, zero, zero};
    float lsum = 0.f;
    bf16x8 kf[4], vcur[8];

    // ---- prologue: K(0) -> S(0) -> P(0) into buf 0; then K(1), V(0) ----
#pragma unroll
    for (int jt = 0; jt < 4; ++jt)
        kf[jt] = *(const bf16x8*)&Kb[(size_t)(jt * 16 + ln) * CKEY + g * 8];
    {
        f32x4 st[4];
#pragma unroll
        for (int jt = 0; jt < 4; ++jt) st[jt] = mfma16(kf[jt], qf, zero);
        bf16_t* Pw0 = &Plds[wave][0][0];
#pragma unroll
        for (int jt = 0; jt < 4; ++jt) {
            bf16x4 p;
#pragma unroll
            for (int r = 0; r < 4; ++r) { float e = __expf(st[jt][r]); lsum += e; p[r] = (bf16_t)e; }
            *(bf16x4*)&Pw0[ln * PSTRIDE + jt * 16 + g * 4] = p;
        }
#pragma unroll
        for (int jt = 0; jt < 4; ++jt)
            kf[jt] = *(const bf16x8*)&Kb[(size_t)(64 + jt * 16 + ln) * CKEY + g * 8];
#pragma unroll
        for (int ct = 0; ct < 4; ++ct) {
            const bf16_t* vp = Vb + (size_t)(c_base + ct * 16 + ln) * N_PIX + g * 8;
            vcur[2 * ct]     = *(const bf16x8*)vp;
            vcur[2 * ct + 1] = *(const bf16x8*)(vp + 32);
        }
    }

    int pbuf = 0;
#pragma unroll 2
    for (int n = 0; n < 64; ++n) {
        const int j0 = n * 64;
        // ---- V(n+1) prefetch (wraps harmlessly on last iter) ----
        const int jv = (j0 + 64) & (N_PIX - 1);
        bf16x8 vnxt[8];
#pragma unroll
        for (int ct = 0; ct < 4; ++ct) {
            const bf16_t* vp = Vb + (size_t)(c_base + ct * 16 + ln) * N_PIX + jv + g * 8;
            vnxt[2 * ct]     = *(const bf16x8*)vp;
            vnxt[2 * ct + 1] = *(const bf16x8*)(vp + 32);
        }
        // ---- S(n+1) from kf = K(n+1) ----
        f32x4 st[4];
#pragma unroll
        for (int jt = 0; jt < 4; ++jt) st[jt] = mfma16(kf[jt], qf, zero);
        // ---- K(n+2) prefetch (wrap keeps addresses in-bounds) ----
        const int jk = (j0 + 128) & (N_PIX - 1);
#pragma unroll
        for (int jt = 0; jt < 4; ++jt)
            kf[jt] = *(const bf16x8*)&Kb[(size_t)(jk + jt * 16 + ln) * CKEY + g * 8];
        // ---- read P(n) from buf pbuf ----
        const bf16_t* Pr = &Plds[wave][pbuf][0];
        const bf16x8 pa0 = *(const bf16x8*)&Pr[ln * PSTRIDE + g * 8];
        const bf16x8 pa1 = *(const bf16x8*)&Pr[ln * PSTRIDE + 32 + g * 8];
        // ---- exp + write P(n+1) to buf pbuf^1; last tile's garbage excluded ----
        bf16_t* Pw = &Plds[wave][pbuf ^ 1][0];
        float ls = 0.f;
#pragma unroll
        for (int jt = 0; jt < 4; ++jt) {
            bf16x4 p;
#pragma unroll
            for (int r = 0; r < 4; ++r) { float e = __expf(st[jt][r]); ls += e; p[r] = (bf16_t)e; }
            *(bf16x4*)&Pw[ln * PSTRIDE + jt * 16 + g * 4] = p;
        }
        if (n < 63) lsum += ls;
        // ---- PV(n): A = V frags (m=c), B = P (n-col = i) ----
#pragma unroll
        for (int ct = 0; ct < 4; ++ct) {
            acc[ct] = mfma16(vcur[2 * ct],     pa0, acc[ct]);
            acc[ct] = mfma16(vcur[2 * ct + 1], pa1, acc[ct]);
        }
#pragma unroll
        for (int k2 = 0; k2 < 8; ++k2) vcur[k2] = vnxt[k2];
        pbuf ^= 1;
    }

    // l_i = sum of the 4 g-group partials for i = ln
    lsum += __shfl_xor(lsum, 16);
    lsum += __shfl_xor(lsum, 32);
    const float s_lane = gamma[0] / lsum;

#pragma unroll
    for (int ct = 0; ct < 4; ++ct)
#pragma unroll
        for (int r = 0; r < 4; ++r) {
            const int c = c_base + ct * 16 + g * 4 + r;   // D row = c_local
            const int i = i_base + ln;                    // D col = i
            const size_t idx = ((size_t)b * CFEAT + c) * N_PIX + i;
            out[idx] = s_lane * acc[ct][r] + features[idx];
        }
}

// ---------------------------------------------------------------------------
extern "C" void kernel_launch(void* const* d_in, const int* in_sizes, int n_in,
                              void* d_out, int out_size, void* d_ws, size_t ws_size,
                              hipStream_t stream) {
    const float* features   = (const float*)d_in[0];
    const float* conditions = (const float*)d_in[1];
    const float* Wq  = (const float*)d_in[2];
    const float* bq  = (const float*)d_in[3];
    const float* Wk  = (const float*)d_in[4];
    const float* bk  = (const float*)d_in[5];
    const float* Wv  = (const float*)d_in[6];
    const float* bv  = (const float*)d_in[7];
    const float* gam = (const float*)d_in[8];
    float* out = (float*)d_out;

    // ws (bf16): Qt 1MB | Kt 1MB | V 8MB | XTf 8MB | XTc 8MB  (~26 MB)
    bf16_t* Qt  = (bf16_t*)d_ws;
    bf16_t* Kt  = Qt  + (size_t)NBATCH * N_PIX * CKEY;
    bf16_t* Vw  = Kt  + (size_t)NBATCH * N_PIX * CKEY;
    bf16_t* XTf = Vw  + (size_t)NBATCH * CFEAT * N_PIX;
    bf16_t* XTc = XTf + (size_t)NBATCH * N_PIX * CFEAT;

    transpose_kernel<<<dim3(N_PIX / 64, CFEAT / 64, 2 * NBATCH), 256, 0, stream>>>(
        features, conditions, XTf, XTc);
    projqk_kernel<<<dim3(N_PIX / 32, NBATCH), 256, 0, stream>>>(
        Wq, bq, Wk, bk, XTc, XTf, Qt, Kt);
    projv_kernel<<<dim3(N_PIX / 64, CFEAT / 64, NBATCH), 256, 0, stream>>>(
        Wv, bv, XTf, Vw);
    pv_kernel<<<dim3(4, N_PIX / 64, NBATCH), 256, 0, stream>>>(
        Qt, Kt, Vw, features, gam, out);
}

// Round 5
// 200.017 us; speedup vs baseline: 2.5506x; 2.5506x over previous
//
#include <hip/hip_runtime.h>

typedef __bf16 bf16_t;
typedef __bf16 bf16x4 __attribute__((ext_vector_type(4)));
typedef __bf16 bf16x8 __attribute__((ext_vector_type(8)));
typedef float f32x4 __attribute__((ext_vector_type(4)));

#define N_PIX 4096
#define CFEAT 256
#define CKEY 32
#define NBATCH 4

static __device__ __forceinline__ f32x4 mfma16(bf16x8 a, bf16x8 b, f32x4 c) {
    return __builtin_amdgcn_mfma_f32_16x16x32_bf16(a, b, c, 0, 0, 0);
}

// async global->LDS, 16B per lane; LDS dest = wave-uniform base + lane*16
static __device__ __forceinline__ void glds16(const void* g, void* l) {
    __builtin_amdgcn_global_load_lds(
        (const __attribute__((address_space(1))) void*)g,
        (__attribute__((address_space(3))) void*)l, 16, 0, 0);
}

// ---------------------------------------------------------------------------
// projqk (round-3 verbatim): Yt[b][n][32] = bf16(W.X + bias), transposed out.
// grid (N/64, 2, B), block 256. LDS repack -> coalesced 16B stores.
// ---------------------------------------------------------------------------
__global__ __launch_bounds__(256) void projqk_kernel(
    const float* __restrict__ Wq, const float* __restrict__ bq, const float* __restrict__ Xq,
    const float* __restrict__ Wk, const float* __restrict__ bk, const float* __restrict__ Xk,
    bf16_t* __restrict__ Qt, bf16_t* __restrict__ Kt)
{
    __shared__ __attribute__((aligned(16))) bf16_t T[64][40];  // [n_local][ck], +8 pad
    const int lane = threadIdx.x & 63, wave = threadIdx.x >> 6;
    const int g = lane >> 4, ln = lane & 15;
    const bool isK = (blockIdx.y == 1);
    const float* W    = isK ? Wk : Wq;
    const float* bias = isK ? bk : bq;
    const float* X  = (isK ? Xk : Xq) + (size_t)blockIdx.z * CFEAT * N_PIX;
    bf16_t*      Yt = (isK ? Kt : Qt) + (size_t)blockIdx.z * N_PIX * CKEY;

    const int m_base = (wave & 1) * 16;                      // ck half
    const int n_loc  = (wave >> 1) * 32;                     // n half within block
    const int n_base = blockIdx.x * 64 + n_loc;

    f32x4 zero = {0.f, 0.f, 0.f, 0.f};
    f32x4 acc[2] = {zero, zero};
    for (int k0 = 0; k0 < CFEAT; k0 += 32) {
        bf16x8 a;
        const float* wp = W + (size_t)(m_base + ln) * CFEAT + k0 + g * 8;
#pragma unroll
        for (int j = 0; j < 8; ++j) a[j] = (bf16_t)wp[j];
#pragma unroll
        for (int nt = 0; nt < 2; ++nt) {
            const float* xp = X + (size_t)(k0 + g * 8) * N_PIX + n_base + nt * 16 + ln;
            bf16x8 bfr;
#pragma unroll
            for (int j = 0; j < 8; ++j) bfr[j] = (bf16_t)xp[(size_t)j * N_PIX];
            acc[nt] = mfma16(a, bfr, acc[nt]);
        }
    }
#pragma unroll
    for (int nt = 0; nt < 2; ++nt)
#pragma unroll
        for (int r = 0; r < 4; ++r) {
            const int ck = m_base + g * 4 + r;
            T[n_loc + nt * 16 + ln][ck] = (bf16_t)(acc[nt][r] + bias[ck]);
        }
    __syncthreads();
    const int n  = threadIdx.x >> 2;
    const int sg = threadIdx.x & 3;
    bf16x8 row = *(const bf16x8*)&T[n][sg * 8];
    *(bf16x8*)&Yt[(size_t)(blockIdx.x * 64 + n) * CKEY + sg * 8] = row;
}

// ---------------------------------------------------------------------------
// projv (round-3 verbatim): V[b][c][n] = bf16(Wv.X + bv). grid (N/32, 2, B).
// ---------------------------------------------------------------------------
__global__ __launch_bounds__(256, 4) void projv_kernel(
    const float* __restrict__ W, const float* __restrict__ bias,
    const float* __restrict__ X, bf16_t* __restrict__ V)
{
    const int lane = threadIdx.x & 63, wave = threadIdx.x >> 6;
    const int g = lane >> 4, ln = lane & 15;
    const int b = blockIdx.z;
    const int n_base = blockIdx.x * 32;
    const int c_wave = blockIdx.y * 128 + wave * 32;
    const float* Xb = X + (size_t)b * CFEAT * N_PIX;
    bf16_t*      Vb = V + (size_t)b * CFEAT * N_PIX;

    f32x4 zero = {0.f, 0.f, 0.f, 0.f};
    f32x4 acc[2][2];
#pragma unroll
    for (int mt = 0; mt < 2; ++mt) { acc[mt][0] = zero; acc[mt][1] = zero; }

    for (int k0 = 0; k0 < CFEAT; k0 += 32) {
        bf16x8 bfr[2];
#pragma unroll
        for (int nt = 0; nt < 2; ++nt) {
            const float* xp = Xb + (size_t)(k0 + g * 8) * N_PIX + n_base + nt * 16 + ln;
#pragma unroll
            for (int j = 0; j < 8; ++j) bfr[nt][j] = (bf16_t)xp[(size_t)j * N_PIX];
        }
#pragma unroll
        for (int mt = 0; mt < 2; ++mt) {
            const float* wp = W + (size_t)(c_wave + mt * 16 + ln) * CFEAT + k0 + g * 8;
            bf16x8 a;
#pragma unroll
            for (int j = 0; j < 8; ++j) a[j] = (bf16_t)wp[j];
            acc[mt][0] = mfma16(a, bfr[0], acc[mt][0]);
            acc[mt][1] = mfma16(a, bfr[1], acc[mt][1]);
        }
    }
#pragma unroll
    for (int mt = 0; mt < 2; ++mt)
#pragma unroll
        for (int nt = 0; nt < 2; ++nt)
#pragma unroll
            for (int r = 0; r < 4; ++r) {
                const int m = c_wave + mt * 16 + g * 4 + r;
                const int n = n_base + nt * 16 + ln;
                Vb[(size_t)m * N_PIX + n] = (bf16_t)(acc[mt][nt][r] + bias[m]);
            }
}

// ---------------------------------------------------------------------------
// pv: out = gamma * softmax(QK^T) V / l + features (max-free softmax).
// m97-style cooperative K-loop:
//   - V tile (64c x 64j = 8KB) staged by all 4 waves via global_load_lds(16B),
//     TRIPLE-buffered, prefetch distance 1, ONE __syncthreads per iteration
//     (its vmcnt(0) drain is the DMA fence; co-resident blocks overlap it).
//   - 16B-granule XOR swizzle slot = c*8 + (jc ^ (c&7)) -> conflict-free b128.
//   - S^T = K.Q^T per wave (stats per-lane); P per-wave-private LDS (no bar).
// grid (4 c-splits, 64 i-tiles, B) = 1024 blocks; 4 blocks/CU.
// ---------------------------------------------------------------------------
#define PSTRIDE 72
__global__ __launch_bounds__(256, 4) void pv_kernel(
    const bf16_t* __restrict__ Qt, const bf16_t* __restrict__ Kt,
    const bf16_t* __restrict__ V,
    const float* __restrict__ features, const float* __restrict__ gamma,
    float* __restrict__ out)
{
    __shared__ __attribute__((aligned(16))) bf16_t Vlds[3][64 * 64];      // 3 x 8KB
    __shared__ __attribute__((aligned(16))) bf16_t Plds[4][16 * PSTRIDE]; // per-wave P^T

    const int lane = threadIdx.x & 63, wave = threadIdx.x >> 6;
    const int g = lane >> 4, ln = lane & 15;
    const int b = blockIdx.z;
    const int i_base = blockIdx.y * 64 + wave * 16;
    const int c_base = blockIdx.x * 64;

    const bf16_t* Qb = Qt + (size_t)b * N_PIX * CKEY;
    const bf16_t* Kb = Kt + (size_t)b * N_PIX * CKEY;
    const bf16_t* Vb = V + (size_t)b * CFEAT * N_PIX;
    bf16_t* Pw = &Plds[wave][0];

    // staging map for this thread's two 16B chunks: slot s -> (c, jc)
    // s in [0,512): c = s>>3, stored jc = (s&7) ^ (c&7)  (XOR swizzle)
    const int s0 = wave * 128 + lane;          // call 0: slots [w*128, w*128+64)
    const int s1 = s0 + 64;                    // call 1
    const int sc0 = s0 >> 3, sj0 = (s0 & 7) ^ (sc0 & 7);
    const int sc1 = s1 >> 3, sj1 = (s1 & 7) ^ (sc1 & 7);
    const bf16_t* vg0 = Vb + (size_t)(c_base + sc0) * N_PIX + sj0 * 8;
    const bf16_t* vg1 = Vb + (size_t)(c_base + sc1) * N_PIX + sj1 * 8;

    // B-frag for S^T: B[k=ck][n=i=ln] = Qt[i][ck]
    const bf16x8 qf = *(const bf16x8*)&Qb[(size_t)(i_base + ln) * CKEY + g * 8];

    f32x4 zero = {0.f, 0.f, 0.f, 0.f};
    f32x4 acc[4] = {zero, zero, zero, zero};
    float lsum = 0.f;

    // prologue: stage V(0) -> buf 0
    glds16(vg0, &Vlds[0][(size_t)(wave * 128) * 8 ]);
    glds16(vg1, &Vlds[0][(size_t)(wave * 128 + 64) * 8 ]);

    int bcur = 0, bnxt = 1;
    for (int n = 0; n < 64; ++n) {
        const int j0 = n * 64;
        // ---- stage V(n+1) into buf bnxt (wraps j on last iter; harmless) ----
        const int jn = (j0 + 64) & (N_PIX - 1);
        glds16(vg0 + jn, &Vlds[bnxt][(size_t)(wave * 128) * 8 ]);
        glds16(vg1 + jn, &Vlds[bnxt][(size_t)(wave * 128 + 64) * 8 ]);

        // ---- S^T(n): A = Kt rows (16B), B = qf; D[row=j_loc][col=i=ln] ----
        f32x4 st[4];
#pragma unroll
        for (int jt = 0; jt < 4; ++jt) {
            const bf16x8 kf = *(const bf16x8*)&Kb[(size_t)(j0 + jt * 16 + ln) * CKEY + g * 8];
            st[jt] = mfma16(kf, qf, zero);
        }
        // ---- exp -> P^T (wave-private LDS, no barrier needed) ----
#pragma unroll
        for (int jt = 0; jt < 4; ++jt) {
            bf16x4 p;
#pragma unroll
            for (int r = 0; r < 4; ++r) { float e = __expf(st[jt][r]); lsum += e; p[r] = (bf16_t)e; }
            *(bf16x4*)&Pw[ln * PSTRIDE + jt * 16 + g * 4] = p;
        }
        const bf16x8 pa0 = *(const bf16x8*)&Pw[ln * PSTRIDE + g * 8];
        const bf16x8 pa1 = *(const bf16x8*)&Pw[ln * PSTRIDE + 32 + g * 8];

        // ---- barrier: drains glds (V(n) ready in bcur from prev iter's
        //      stage + this barrier for n==0 prologue), recycles buffers ----
        __syncthreads();

        // ---- PV(n): A = V frags from LDS (swizzled), B = P^T frags ----
        const bf16_t* Vt = &Vlds[bcur][0];
#pragma unroll
        for (int ct = 0; ct < 4; ++ct) {
            const int c = ct * 16 + ln;
            // h = 0: jc16 = g ; h = 1: jc16 = 4 + g
            const int sl0 = c * 8 + ((g)     ^ (c & 7));
            const int sl1 = c * 8 + ((4 + g) ^ (c & 7));
            const bf16x8 v0 = *(const bf16x8*)&Vt[sl0 * 8];
            const bf16x8 v1 = *(const bf16x8*)&Vt[sl1 * 8];
            acc[ct] = mfma16(v0, pa0, acc[ct]);
            acc[ct] = mfma16(v1, pa1, acc[ct]);
        }
        // rotate triple buffer
        const int bold = bcur;
        bcur = bnxt;
        bnxt = (bnxt == 2) ? 0 : (bnxt + 1);
        (void)bold;
    }

    // l_i: sum the 4 g-group partials for i = ln
    lsum += __shfl_xor(lsum, 16);
    lsum += __shfl_xor(lsum, 32);
    const float s_lane = gamma[0] / lsum;

#pragma unroll
    for (int ct = 0; ct < 4; ++ct)
#pragma unroll
        for (int r = 0; r < 4; ++r) {
            const int c = c_base + ct * 16 + g * 4 + r;   // D row = c_local
            const int i = i_base + ln;                    // D col = i
            const size_t idx = ((size_t)b * CFEAT + c) * N_PIX + i;
            out[idx] = s_lane * acc[ct][r] + features[idx];
        }
}

// ---------------------------------------------------------------------------
extern "C" void kernel_launch(void* const* d_in, const int* in_sizes, int n_in,
                              void* d_out, int out_size, void* d_ws, size_t ws_size,
                              hipStream_t stream) {
    const float* features   = (const float*)d_in[0];
    const float* conditions = (const float*)d_in[1];
    const float* Wq  = (const float*)d_in[2];
    const float* bq  = (const float*)d_in[3];
    const float* Wk  = (const float*)d_in[4];
    const float* bk  = (const float*)d_in[5];
    const float* Wv  = (const float*)d_in[6];
    const float* bv  = (const float*)d_in[7];
    const float* gam = (const float*)d_in[8];
    float* out = (float*)d_out;

    // ws (bf16): Qt 1MB | Kt 1MB | V 8MB
    bf16_t* Qt = (bf16_t*)d_ws;
    bf16_t* Kt = Qt + (size_t)NBATCH * N_PIX * CKEY;
    bf16_t* Vw = Kt + (size_t)NBATCH * N_PIX * CKEY;

    projqk_kernel<<<dim3(N_PIX / 64, 2, NBATCH), 256, 0, stream>>>(
        Wq, bq, conditions, Wk, bk, features, Qt, Kt);
    projv_kernel<<<dim3(N_PIX / 32, 2, NBATCH), 256, 0, stream>>>(Wv, bv, features, Vw);
    pv_kernel<<<dim3(4, N_PIX / 64, NBATCH), 256, 0, stream>>>(
        Qt, Kt, Vw, features, gam, out);
}